// Round 3
// baseline (4700.454 us; speedup 1.0000x reference)
//
#include <hip/hip_runtime.h>
#include <cstddef>

#define S_LEN 2048
#define B_SZ  64
#define I_DIM 256
#define H_DIM 512

// ---------------------------------------------------------------------------
// Kernel A: projection GEMM (unchanged — validated).
//   out[m, n] = sum_k X[m,k] * W_ih[n,k] + b_ih[n] + b_hh[n]
// ---------------------------------------------------------------------------
#define BM 64
#define BN 64
#define BK 32

__global__ __launch_bounds__(256) void proj_gemm(
        const float* __restrict__ X, const float* __restrict__ W,
        const float* __restrict__ b_ih, const float* __restrict__ b_hh,
        float* __restrict__ out) {
    __shared__ float As[BK][BM + 4];
    __shared__ float Bs[BK][BN + 4];

    const int t    = threadIdx.x;
    const int row0 = blockIdx.y * BM;
    const int col0 = blockIdx.x * BN;
    const int ty   = t >> 4;
    const int tx   = t & 15;

    float acc[4][4];
#pragma unroll
    for (int i = 0; i < 4; ++i)
#pragma unroll
        for (int j = 0; j < 4; ++j) acc[i][j] = 0.f;

    for (int kb = 0; kb < I_DIM; kb += BK) {
#pragma unroll
        for (int r = 0; r < 2; ++r) {
            const int idx = t + r * 256;
            const int m   = idx >> 3;
            const int k4  = idx & 7;
            float4 va = *(const float4*)(X + (size_t)(row0 + m) * I_DIM + kb + k4 * 4);
            As[k4 * 4 + 0][m] = va.x;
            As[k4 * 4 + 1][m] = va.y;
            As[k4 * 4 + 2][m] = va.z;
            As[k4 * 4 + 3][m] = va.w;
            float4 vb = *(const float4*)(W + (size_t)(col0 + m) * I_DIM + kb + k4 * 4);
            Bs[k4 * 4 + 0][m] = vb.x;
            Bs[k4 * 4 + 1][m] = vb.y;
            Bs[k4 * 4 + 2][m] = vb.z;
            Bs[k4 * 4 + 3][m] = vb.w;
        }
        __syncthreads();
#pragma unroll
        for (int kk = 0; kk < BK; ++kk) {
            float4 a = *(const float4*)&As[kk][ty * 4];
            float4 b = *(const float4*)&Bs[kk][tx * 4];
            const float av[4] = {a.x, a.y, a.z, a.w};
            const float bv[4] = {b.x, b.y, b.z, b.w};
#pragma unroll
            for (int i = 0; i < 4; ++i)
#pragma unroll
                for (int j = 0; j < 4; ++j)
                    acc[i][j] = fmaf(av[i], bv[j], acc[i][j]);
        }
        __syncthreads();
    }

    float bias[4];
#pragma unroll
    for (int j = 0; j < 4; ++j) {
        const int n = col0 + tx * 4 + j;
        bias[j] = b_ih[n] + b_hh[n];
    }
#pragma unroll
    for (int i = 0; i < 4; ++i) {
        const int m = row0 + ty * 4 + i;
        float4 o;
        o.x = acc[i][0] + bias[0];
        o.y = acc[i][1] + bias[1];
        o.z = acc[i][2] + bias[2];
        o.w = acc[i][3] + bias[3];
        *(float4*)(out + (size_t)m * H_DIM + col0 + tx * 4) = o;
    }
}

// ---------------------------------------------------------------------------
// Kernel B v6: round-4 protocol VERBATIM + register-resident W + cooperative
// launch for guaranteed co-residency.
//
// v5 post-mortem: v5 ran but failed absmax=1.65 (tanh-bounded garbage =
// polls bailed). Protocol audit found no logic bug; the structural change
// was occupancy 2 wg/CU -> 1 wg/CU with ZERO residency slack (128 W-floats
// per thread -> VGPR>128 -> 8 waves/CU cap -> 256 wgs on 256 CUs exact-fit).
// Non-resident partner => spin => 4M-iter bail => tanh(wrong z). Fix:
// (1) revert to the round-4 mailbox protocol verbatim (3 barriers/step,
//     all-512-lane 32-bit atomicExch both sides, identical FMA/z order —
//     the exact configuration that PASSED at 4467 us);
// (2) keep only the W-register fix (32 named float4, REP32) — the L2-BW
//     bottleneck fix: round-4 streamed 256 KB/wg/step of W from L2 =
//     34.1 TB/s == the L2 ceiling over the whole 3938 us scan;
// (3) __launch_bounds__(512, 2): hard VGPR cap 256 so the 8-wave block is
//     always launchable;
// (4) hipLaunchCooperativeKernel: HW-guaranteed co-residency of all 256
//     wgs at 1 wg/CU (no grid.sync used — residency guarantee only).
// ---------------------------------------------------------------------------
#define SENT 0xAAAAAAAAu

#define REP32(M) M(0) M(1) M(2) M(3) M(4) M(5) M(6) M(7) \
                 M(8) M(9) M(10) M(11) M(12) M(13) M(14) M(15) \
                 M(16) M(17) M(18) M(19) M(20) M(21) M(22) M(23) \
                 M(24) M(25) M(26) M(27) M(28) M(29) M(30) M(31)

__global__ __launch_bounds__(512, 2) void rnn_scan_v6(
        const float* __restrict__ W_hh, const float* __restrict__ h0,
        float* __restrict__ out, unsigned* __restrict__ mb) {
    const int bid   = blockIdx.x;
    const int b     = bid & 63;   // batch  (group {b,b+64,b+128,b+192} == b mod 8 -> same XCD)
    const int slice = bid >> 6;   // 0..3: this wg's output column slice
    const int t     = threadIdx.x;
    const int q     = t >> 7;     // 0..3: k-chunk / consumer id
    const int j     = t & 127;
    const int col   = slice * 128 + j;

    __shared__ __align__(16) float h_lds[H_DIM];
    __shared__ float part[4][128];
    __shared__ float hn_s[128];

    // W rows for this wg's 128 output columns, forced into registers:
    // thread t holds W_hh[col][q*128 .. q*128+127] as 32 named float4.
    const float4* wr = (const float4*)(W_hh + (size_t)col * H_DIM + q * 128);
#define WLD(i) const float4 w##i = wr[i];
    REP32(WLD)
#undef WLD

    h_lds[t] = h0[(size_t)b * H_DIM + t];
    __syncthreads();

    float* outb = out + (size_t)b * (size_t)S_LEN * H_DIM;
    bool alive = true;

    for (int s = 0; s < S_LEN; ++s) {
        // Prefetch xp (overlaps the poll below).
        float xp = 0.f;
        if (t < 128) xp = outb[(size_t)s * H_DIM + slice * 128 + t];

        if (s > 0) {
            const int ph = (s - 1) & 1;
            unsigned* src = mb + (((size_t)ph * 4 + slice) * B_SZ + b) * H_DIM + t;
            unsigned v = SENT;
            if (alive) {
                int iters = 0;
                do {
                    v = atomicExch(src, SENT);   // real RMW; auto-re-arms slot
                    if (v != SENT) break;
                } while (++iters < 4000000);
                if (v == SENT) alive = false;    // bail instead of hanging
            }
            h_lds[t] = __uint_as_float(v);
            __syncthreads();
        }

        // Partial dot: 128 register-FMAs vs LDS h segment, 4 accumulators.
        // Accumulation order identical to the round-4 passing kernel:
        // a0 += w[4i+0]*h[4i+0], a1 += w[4i+1]*h[4i+1], ...
        const float4* h4 = (const float4*)&h_lds[q * 128];
        float a0 = 0.f, a1 = 0.f, a2 = 0.f, a3 = 0.f;
#define FMA4(i) { const float4 hv = h4[i];            \
                  a0 = fmaf(w##i.x, hv.x, a0);        \
                  a1 = fmaf(w##i.y, hv.y, a1);        \
                  a2 = fmaf(w##i.z, hv.z, a2);        \
                  a3 = fmaf(w##i.w, hv.w, a3); }
        REP32(FMA4)
#undef FMA4
        part[q][j] = (a0 + a1) + (a2 + a3);
        __syncthreads();

        if (t < 128) {
            float z  = xp + part[0][t] + part[1][t] + part[2][t] + part[3][t];
            float hn = tanhf(z);
            hn_s[t] = hn;
            outb[(size_t)s * H_DIM + slice * 128 + t] = hn;
        }
        __syncthreads();

        // Publish: all 512 threads push hn_s to consumer mailbox q (= t>>7).
        {
            const int ph = s & 1;
            unsigned* dst = mb + (((size_t)ph * 4 + q) * B_SZ + b) * H_DIM
                               + slice * 128 + j;
            atomicExch(dst, __float_as_uint(hn_s[j]));
        }
        // No trailing barrier needed: next iteration's h_lds write is gated
        // by the post-poll __syncthreads before any thread's FMA reads it.
    }
}

// ---------------------------------------------------------------------------
extern "C" void kernel_launch(void* const* d_in, const int* in_sizes, int n_in,
                              void* d_out, int out_size, void* d_ws, size_t ws_size,
                              hipStream_t stream) {
    const float* x_in = (const float*)d_in[0];
    const float* h0   = (const float*)d_in[1];
    const float* W_ih = (const float*)d_in[2];
    const float* W_hh = (const float*)d_in[3];
    const float* b_ih = (const float*)d_in[4];
    const float* b_hh = (const float*)d_in[5];
    float* out   = (float*)d_out;
    unsigned* mb = (unsigned*)d_ws;   // 2*4*64*512*4 = 1 MB

    // 1) x_proj (+biases) straight into d_out.
    dim3 gA(H_DIM / BN, (B_SZ * S_LEN) / BM);
    proj_gemm<<<gA, 256, 0, stream>>>(x_in, W_ih, b_ih, b_hh, out);

    // 2) Arm all mailboxes with the sentinel (both phases).
    hipMemsetAsync(d_ws, 0xAA, (size_t)2 * 4 * B_SZ * H_DIM * sizeof(unsigned),
                   stream);

    // 3) Scan: cooperative launch => all 256 wgs co-resident by guarantee.
    //    (No grid sync inside; cooperative is purely the residency contract.)
    void* args[] = {(void*)&W_hh, (void*)&h0, (void*)&out, (void*)&mb};
    hipError_t e = hipLaunchCooperativeKernel(
        (const void*)rnn_scan_v6, dim3(4 * B_SZ), dim3(512), args, 0, stream);
    if (e != hipSuccess) {
        // Fallback (non-capture path safety): plain launch, same grid.
        rnn_scan_v6<<<dim3(4 * B_SZ), 512, 0, stream>>>(W_hh, h0, out, mb);
    }
}

// Round 9
// 4609.832 us; speedup vs baseline: 1.0197x; 1.0197x over previous
//
#include <hip/hip_runtime.h>
#include <cstddef>

#define S_LEN 2048
#define B_SZ  64
#define I_DIM 256
#define H_DIM 512

// ---------------------------------------------------------------------------
// Kernel A: projection GEMM (unchanged — validated).
//   out[m, n] = sum_k X[m,k] * W_ih[n,k] + b_ih[n] + b_hh[n]
// ---------------------------------------------------------------------------
#define BM 64
#define BN 64
#define BK 32

__global__ __launch_bounds__(256) void proj_gemm(
        const float* __restrict__ X, const float* __restrict__ W,
        const float* __restrict__ b_ih, const float* __restrict__ b_hh,
        float* __restrict__ out) {
    __shared__ float As[BK][BM + 4];
    __shared__ float Bs[BK][BN + 4];

    const int t    = threadIdx.x;
    const int row0 = blockIdx.y * BM;
    const int col0 = blockIdx.x * BN;
    const int ty   = t >> 4;
    const int tx   = t & 15;

    float acc[4][4];
#pragma unroll
    for (int i = 0; i < 4; ++i)
#pragma unroll
        for (int j = 0; j < 4; ++j) acc[i][j] = 0.f;

    for (int kb = 0; kb < I_DIM; kb += BK) {
#pragma unroll
        for (int r = 0; r < 2; ++r) {
            const int idx = t + r * 256;
            const int m   = idx >> 3;
            const int k4  = idx & 7;
            float4 va = *(const float4*)(X + (size_t)(row0 + m) * I_DIM + kb + k4 * 4);
            As[k4 * 4 + 0][m] = va.x;
            As[k4 * 4 + 1][m] = va.y;
            As[k4 * 4 + 2][m] = va.z;
            As[k4 * 4 + 3][m] = va.w;
            float4 vb = *(const float4*)(W + (size_t)(col0 + m) * I_DIM + kb + k4 * 4);
            Bs[k4 * 4 + 0][m] = vb.x;
            Bs[k4 * 4 + 1][m] = vb.y;
            Bs[k4 * 4 + 2][m] = vb.z;
            Bs[k4 * 4 + 3][m] = vb.w;
        }
        __syncthreads();
#pragma unroll
        for (int kk = 0; kk < BK; ++kk) {
            float4 a = *(const float4*)&As[kk][ty * 4];
            float4 b = *(const float4*)&Bs[kk][tx * 4];
            const float av[4] = {a.x, a.y, a.z, a.w};
            const float bv[4] = {b.x, b.y, b.z, b.w};
#pragma unroll
            for (int i = 0; i < 4; ++i)
#pragma unroll
                for (int j = 0; j < 4; ++j)
                    acc[i][j] = fmaf(av[i], bv[j], acc[i][j]);
        }
        __syncthreads();
    }

    float bias[4];
#pragma unroll
    for (int j = 0; j < 4; ++j) {
        const int n = col0 + tx * 4 + j;
        bias[j] = b_ih[n] + b_hh[n];
    }
#pragma unroll
    for (int i = 0; i < 4; ++i) {
        const int m = row0 + ty * 4 + i;
        float4 o;
        o.x = acc[i][0] + bias[0];
        o.y = acc[i][1] + bias[1];
        o.z = acc[i][2] + bias[2];
        o.w = acc[i][3] + bias[3];
        *(float4*)(out + (size_t)m * H_DIM + col0 + tx * 4) = o;
    }
}

// ---------------------------------------------------------------------------
// Kernel B v8: SCALAR-pinned register-resident W + 4col x 32k chunking.
//
// v7 post-mortem: compile error — AMDGPU backend rejects tied "+v" on a
// 128-bit float4 ("tied indirect register inputs"). Tied "+v" on scalar
// float IS supported (standard pattern). Fix: dwordx4 loads unchanged, but
// unpack each float4 into 4 NAMED SCALAR floats and pin those (128 scalar
// "+v" constraints in groups of 4). Volatile-asm outputs cannot be deleted,
// duplicated, sunk, or rematerialized => regalloc must keep all 128 W
// values in VGPRs across the scan loop (~180 total < 256 cap from
// __launch_bounds__(512,2)).
//
// Carried from v7 (unmeasured but audited):
//  - 4col x 32k chunking: each h-broadcast ds_read_b128 feeds 16 FMAs;
//    LDS reads/thread/step 32 -> 8.
//  - part[] 16-partial reduction, ascending-k (fp32 reassociation only).
// Carried from v6 (PASSED): mailbox protocol, barriers, poll/publish
// indexing byte-identical; cooperative launch = co-residency guarantee.
//
// Standing theory: scan is L2-BW-bound streaming W_hh (256 KB/wg/step =
// 34 TB/s == L2 ceiling, VGPR=112 proves W never stayed resident).
// Predictions: VGPR >=160; scan ~4100 -> 700-1300 us; total -> 1400-2000 us.
// ---------------------------------------------------------------------------
#define SENT 0xAAAAAAAAu

__global__ __launch_bounds__(512, 2) void rnn_scan_v8(
        const float* __restrict__ W_hh, const float* __restrict__ h0,
        float* __restrict__ out, unsigned* __restrict__ mb) {
    const int bid   = blockIdx.x;
    const int b     = bid & 63;   // batch ({b,b+64,b+128,b+192} == b mod 8 -> same XCD)
    const int slice = bid >> 6;   // 0..3: output column slice of 128
    const int t     = threadIdx.x;

    // FMA-phase decomposition: thread owns cols [colbase, colbase+4) and
    // k-chunk [q*32, q*32+32).
    const int c  = t & 31;        // col group 0..31
    const int q  = t >> 5;        // k-chunk 0..15
    const int colbase = slice * 128 + c * 4;

    // Publish-phase decomposition (v6-identical).
    const int qp = t >> 7;        // consumer wg 0..3
    const int jp = t & 127;

    __shared__ __align__(16) float h_lds[H_DIM];
    __shared__ __align__(16) float part[16][128];
    __shared__ float hn_s[128];

    // --- W load: 4 rows x 8 float4 = 128 floats/thread, unpacked to named
    //     scalars (loads stay dwordx4; unpack is register-level, free).
    const float4* w0p = (const float4*)(W_hh + (size_t)(colbase + 0) * H_DIM + q * 32);
    const float4* w1p = (const float4*)(W_hh + (size_t)(colbase + 1) * H_DIM + q * 32);
    const float4* w2p = (const float4*)(W_hh + (size_t)(colbase + 2) * H_DIM + q * 32);
    const float4* w3p = (const float4*)(W_hh + (size_t)(colbase + 3) * H_DIM + q * 32);

#define WLOAD(R,K) \
    float w_##R##_##K##x, w_##R##_##K##y, w_##R##_##K##z, w_##R##_##K##w; \
    { const float4 v_ = w##R##p[K]; \
      w_##R##_##K##x = v_.x; w_##R##_##K##y = v_.y; \
      w_##R##_##K##z = v_.z; w_##R##_##K##w = v_.w; }
#define WROW(R) WLOAD(R,0) WLOAD(R,1) WLOAD(R,2) WLOAD(R,3) \
                WLOAD(R,4) WLOAD(R,5) WLOAD(R,6) WLOAD(R,7)
    WROW(0) WROW(1) WROW(2) WROW(3)
#undef WROW
#undef WLOAD

    // Pin: volatile-asm redefinition of each SCALAR — cannot be sunk,
    // duplicated, or rematerialized; forces true VGPR residency.
#define PIN(R,K) asm volatile("" : "+v"(w_##R##_##K##x), "+v"(w_##R##_##K##y), \
                                   "+v"(w_##R##_##K##z), "+v"(w_##R##_##K##w));
#define PINROW(R) PIN(R,0) PIN(R,1) PIN(R,2) PIN(R,3) \
                  PIN(R,4) PIN(R,5) PIN(R,6) PIN(R,7)
    PINROW(0) PINROW(1) PINROW(2) PINROW(3)
#undef PINROW
#undef PIN

    h_lds[t] = h0[(size_t)b * H_DIM + t];
    __syncthreads();

    float* outb = out + (size_t)b * (size_t)S_LEN * H_DIM;
    bool alive = true;

    for (int s = 0; s < S_LEN; ++s) {
        // Prefetch xp (overlaps the poll below).
        float xp = 0.f;
        if (t < 128) xp = outb[(size_t)s * H_DIM + slice * 128 + t];

        if (s > 0) {
            const int ph = (s - 1) & 1;
            unsigned* src = mb + (((size_t)ph * 4 + slice) * B_SZ + b) * H_DIM + t;
            unsigned v = SENT;
            if (alive) {
                int iters = 0;
                do {
                    v = atomicExch(src, SENT);   // real RMW; auto-re-arms slot
                    if (v != SENT) break;
                } while (++iters < 4000000);
                if (v == SENT) alive = false;    // bail instead of hanging
            }
            h_lds[t] = __uint_as_float(v);
            __syncthreads();
        }

        // Partial dots: 8 broadcast ds_read_b128, 128 register FMAs,
        // 4 accumulator chains (ILP hides FMA latency).
        const float4* h4 = (const float4*)&h_lds[q * 32];
        float a0 = 0.f, a1 = 0.f, a2 = 0.f, a3 = 0.f;
#define FMA8(K) { const float4 hv = h4[K];                                 \
        a0 = fmaf(w_0_##K##x, hv.x, a0); a0 = fmaf(w_0_##K##y, hv.y, a0);  \
        a0 = fmaf(w_0_##K##z, hv.z, a0); a0 = fmaf(w_0_##K##w, hv.w, a0);  \
        a1 = fmaf(w_1_##K##x, hv.x, a1); a1 = fmaf(w_1_##K##y, hv.y, a1);  \
        a1 = fmaf(w_1_##K##z, hv.z, a1); a1 = fmaf(w_1_##K##w, hv.w, a1);  \
        a2 = fmaf(w_2_##K##x, hv.x, a2); a2 = fmaf(w_2_##K##y, hv.y, a2);  \
        a2 = fmaf(w_2_##K##z, hv.z, a2); a2 = fmaf(w_2_##K##w, hv.w, a2);  \
        a3 = fmaf(w_3_##K##x, hv.x, a3); a3 = fmaf(w_3_##K##y, hv.y, a3);  \
        a3 = fmaf(w_3_##K##z, hv.z, a3); a3 = fmaf(w_3_##K##w, hv.w, a3); }
        FMA8(0) FMA8(1) FMA8(2) FMA8(3) FMA8(4) FMA8(5) FMA8(6) FMA8(7)
#undef FMA8
        float4 pv;
        pv.x = a0; pv.y = a1; pv.z = a2; pv.w = a3;
        *(float4*)&part[q][c * 4] = pv;   // contiguous 16B, conflict-free
        __syncthreads();

        if (t < 128) {
            // z = xp + chunk partials in ascending-k order.
            float z = xp;
#pragma unroll
            for (int qq = 0; qq < 16; ++qq) z += part[qq][t];
            float hn = tanhf(z);
            hn_s[t] = hn;
            outb[(size_t)s * H_DIM + slice * 128 + t] = hn;
        }
        __syncthreads();

        // Publish (v6-identical): all 512 threads push hn_s to consumer qp.
        {
            const int ph = s & 1;
            unsigned* dst = mb + (((size_t)ph * 4 + qp) * B_SZ + b) * H_DIM
                               + slice * 128 + jp;
            atomicExch(dst, __float_as_uint(hn_s[jp]));
        }
        // No trailing barrier: next h_lds write is gated by the post-poll
        // __syncthreads before any FMA reads it.
    }
}

// ---------------------------------------------------------------------------
extern "C" void kernel_launch(void* const* d_in, const int* in_sizes, int n_in,
                              void* d_out, int out_size, void* d_ws, size_t ws_size,
                              hipStream_t stream) {
    const float* x_in = (const float*)d_in[0];
    const float* h0   = (const float*)d_in[1];
    const float* W_ih = (const float*)d_in[2];
    const float* W_hh = (const float*)d_in[3];
    const float* b_ih = (const float*)d_in[4];
    const float* b_hh = (const float*)d_in[5];
    float* out   = (float*)d_out;
    unsigned* mb = (unsigned*)d_ws;   // 2*4*64*512*4 = 1 MB

    // 1) x_proj (+biases) straight into d_out.
    dim3 gA(H_DIM / BN, (B_SZ * S_LEN) / BM);
    proj_gemm<<<gA, 256, 0, stream>>>(x_in, W_ih, b_ih, b_hh, out);

    // 2) Arm all mailboxes with the sentinel (both phases).
    hipMemsetAsync(d_ws, 0xAA, (size_t)2 * 4 * B_SZ * H_DIM * sizeof(unsigned),
                   stream);

    // 3) Scan: cooperative launch => co-residency by guarantee (no grid sync
    //    used; residency contract only).
    void* args[] = {(void*)&W_hh, (void*)&h0, (void*)&out, (void*)&mb};
    hipError_t e = hipLaunchCooperativeKernel(
        (const void*)rnn_scan_v8, dim3(4 * B_SZ), dim3(512), args, 0, stream);
    if (e != hipSuccess) {
        rnn_scan_v8<<<dim3(4 * B_SZ), 512, 0, stream>>>(W_hh, h0, out, mb);
    }
}

// Round 10
// 4093.768 us; speedup vs baseline: 1.1482x; 1.1261x over previous
//
#include <hip/hip_runtime.h>
#include <cstddef>

#define S_LEN 2048
#define B_SZ  64
#define I_DIM 256
#define H_DIM 512

// ---------------------------------------------------------------------------
// Kernel A: projection GEMM (unchanged — validated).
// ---------------------------------------------------------------------------
#define BM 64
#define BN 64
#define BK 32

__global__ __launch_bounds__(256) void proj_gemm(
        const float* __restrict__ X, const float* __restrict__ W,
        const float* __restrict__ b_ih, const float* __restrict__ b_hh,
        float* __restrict__ out) {
    __shared__ float As[BK][BM + 4];
    __shared__ float Bs[BK][BN + 4];

    const int t    = threadIdx.x;
    const int row0 = blockIdx.y * BM;
    const int col0 = blockIdx.x * BN;
    const int ty   = t >> 4;
    const int tx   = t & 15;

    float acc[4][4];
#pragma unroll
    for (int i = 0; i < 4; ++i)
#pragma unroll
        for (int j = 0; j < 4; ++j) acc[i][j] = 0.f;

    for (int kb = 0; kb < I_DIM; kb += BK) {
#pragma unroll
        for (int r = 0; r < 2; ++r) {
            const int idx = t + r * 256;
            const int m   = idx >> 3;
            const int k4  = idx & 7;
            float4 va = *(const float4*)(X + (size_t)(row0 + m) * I_DIM + kb + k4 * 4);
            As[k4 * 4 + 0][m] = va.x;
            As[k4 * 4 + 1][m] = va.y;
            As[k4 * 4 + 2][m] = va.z;
            As[k4 * 4 + 3][m] = va.w;
            float4 vb = *(const float4*)(W + (size_t)(col0 + m) * I_DIM + kb + k4 * 4);
            Bs[k4 * 4 + 0][m] = vb.x;
            Bs[k4 * 4 + 1][m] = vb.y;
            Bs[k4 * 4 + 2][m] = vb.z;
            Bs[k4 * 4 + 3][m] = vb.w;
        }
        __syncthreads();
#pragma unroll
        for (int kk = 0; kk < BK; ++kk) {
            float4 a = *(const float4*)&As[kk][ty * 4];
            float4 b = *(const float4*)&Bs[kk][tx * 4];
            const float av[4] = {a.x, a.y, a.z, a.w};
            const float bv[4] = {b.x, b.y, b.z, b.w};
#pragma unroll
            for (int i = 0; i < 4; ++i)
#pragma unroll
                for (int j = 0; j < 4; ++j)
                    acc[i][j] = fmaf(av[i], bv[j], acc[i][j]);
        }
        __syncthreads();
    }

    float bias[4];
#pragma unroll
    for (int j = 0; j < 4; ++j) {
        const int n = col0 + tx * 4 + j;
        bias[j] = b_ih[n] + b_hh[n];
    }
#pragma unroll
    for (int i = 0; i < 4; ++i) {
        const int m = row0 + ty * 4 + i;
        float4 o;
        o.x = acc[i][0] + bias[0];
        o.y = acc[i][1] + bias[1];
        o.z = acc[i][2] + bias[2];
        o.w = acc[i][3] + bias[3];
        *(float4*)(out + (size_t)m * H_DIM + col0 + tx * 4) = o;
    }
}

// ---------------------------------------------------------------------------
// Kernel B v9: sync-latency attack.
//
// v8 post-mortem: dur IDENTICAL to v6 (3.94 vs 3.93 ms) across two very
// different compute structures, VALUBusy halved (33->16%), no scratch
// traffic in FETCH (W is resident in the unified AGPR file; arch-VGPR=88
// is why the counter didn't jump). => the scan is LATENCY-bound on the
// per-step cross-wg sync chain: 3936us/2048 = 1.92us/step. v6's L2 W-stream
// (1.86us/step of BW demand) was hidden UNDER this latency; both walls were
// coincidentally equal, which is why fixing W changed nothing.
//
// 4-wg/batch structure is forced (W=1MB exceeds any 1-2 CU register file),
// so v9 shaves the sync chain itself — transport changes only, the v6-proven
// causal protocol (2-phase mailbox, one-writer/one-reader per address,
// RMW on both sides, consumer-poll re-arms, producer gated by consumption
// causality) is unchanged:
//  (1) publish IMMEDIATELY after tanh from registers (hn_s + barrier#3
//      deleted; pair value via __shfl_down) — cuts ~0.2us off the path.
//  (2) double-pumped poll: 2 outstanding RMWs per loop iteration halves the
//      sampling period => discovery latency ~ -RTT/2.
//  (3) 8B packed payloads (2 floats / atomicExch) + self-slice bypass (own
//      chunk register->LDS direct; publish only to 3 remote consumers):
//      fabric RMWs/wg/step ~1100 -> ~600 (less queueing, shorter tail).
// Barriers/step: 3 -> 2. FMA/z arithmetic order identical to v8 (passing).
// ---------------------------------------------------------------------------
#define SENT2 0xAAAAAAAAAAAAAAAAull

__global__ __launch_bounds__(512, 2) void rnn_scan_v9(
        const float* __restrict__ W_hh, const float* __restrict__ h0,
        float* __restrict__ out, unsigned long long* __restrict__ mb) {
    const int bid   = blockIdx.x;
    const int b     = bid & 63;   // batch ({b,b+64,b+128,b+192} == b mod 8 -> same XCD)
    const int slice = bid >> 6;   // 0..3: output column slice of 128
    const int t     = threadIdx.x;

    // FMA-phase decomposition (v8-identical): 4 cols x 32 k per thread.
    const int c  = t & 31;
    const int q  = t >> 5;
    const int colbase = slice * 128 + c * 4;

    __shared__ __align__(16) float h_lds[H_DIM];
    __shared__ __align__(16) float part[16][128];

    // --- W load + scalar pins (v8-identical; W ends up register-resident) --
    const float4* w0p = (const float4*)(W_hh + (size_t)(colbase + 0) * H_DIM + q * 32);
    const float4* w1p = (const float4*)(W_hh + (size_t)(colbase + 1) * H_DIM + q * 32);
    const float4* w2p = (const float4*)(W_hh + (size_t)(colbase + 2) * H_DIM + q * 32);
    const float4* w3p = (const float4*)(W_hh + (size_t)(colbase + 3) * H_DIM + q * 32);

#define WLOAD(R,K) \
    float w_##R##_##K##x, w_##R##_##K##y, w_##R##_##K##z, w_##R##_##K##w; \
    { const float4 v_ = w##R##p[K]; \
      w_##R##_##K##x = v_.x; w_##R##_##K##y = v_.y; \
      w_##R##_##K##z = v_.z; w_##R##_##K##w = v_.w; }
#define WROW(R) WLOAD(R,0) WLOAD(R,1) WLOAD(R,2) WLOAD(R,3) \
                WLOAD(R,4) WLOAD(R,5) WLOAD(R,6) WLOAD(R,7)
    WROW(0) WROW(1) WROW(2) WROW(3)
#undef WROW
#undef WLOAD

#define PIN(R,K) asm volatile("" : "+v"(w_##R##_##K##x), "+v"(w_##R##_##K##y), \
                                   "+v"(w_##R##_##K##z), "+v"(w_##R##_##K##w));
#define PINROW(R) PIN(R,0) PIN(R,1) PIN(R,2) PIN(R,3) \
                  PIN(R,4) PIN(R,5) PIN(R,6) PIN(R,7)
    PINROW(0) PINROW(1) PINROW(2) PINROW(3)
#undef PINROW
#undef PIN

    h_lds[t] = h0[(size_t)b * H_DIM + t];
    __syncthreads();

    float* outb = out + (size_t)b * (size_t)S_LEN * H_DIM;
    bool alive = true;

    // ull mailbox: mb[ph(2)][cons(4)][b(64)][pair(256)]
    // pair p holds (h[2p], h[2p+1]); producer slice owns pairs
    // [slice*64, slice*64+64). Poller thread t (t<256) reads pair t; pairs
    // with t>>6 == slice are own-slice (direct LDS write, no mailbox).

    for (int s = 0; s < S_LEN; ++s) {
        // xp prefetch (overlaps the poll).
        float xp = 0.f;
        if (t < 128) xp = outb[(size_t)s * H_DIM + slice * 128 + t];

        if (s > 0) {
            if (t < 256 && (t >> 6) != slice) {
                const int ph = (s - 1) & 1;
                unsigned long long* src =
                    mb + ((size_t)(ph * 4 + slice) * B_SZ + b) * 256 + t;
                unsigned long long v = SENT2;
                if (alive) {
                    int it = 0;
                    do {
                        // double-pumped: 2 outstanding RMWs per iteration.
                        unsigned long long v1 = atomicExch(src, SENT2);
                        unsigned long long v2 = atomicExch(src, SENT2);
                        v = (v1 != SENT2) ? v1 : v2;
                    } while (v == SENT2 && ++it < 2000000);
                    if (v == SENT2) alive = false;   // bail, never hang
                }
                h_lds[2 * t]     = __uint_as_float((unsigned)(v & 0xffffffffull));
                h_lds[2 * t + 1] = __uint_as_float((unsigned)(v >> 32));
            }
            __syncthreads();   // barrier #1: h_lds complete
        }

        // Partial dots (v8-identical): 8 broadcast ds_read_b128, 128 FMAs.
        const float4* h4 = (const float4*)&h_lds[q * 32];
        float a0 = 0.f, a1 = 0.f, a2 = 0.f, a3 = 0.f;
#define FMA8(K) { const float4 hv = h4[K];                                 \
        a0 = fmaf(w_0_##K##x, hv.x, a0); a0 = fmaf(w_0_##K##y, hv.y, a0);  \
        a0 = fmaf(w_0_##K##z, hv.z, a0); a0 = fmaf(w_0_##K##w, hv.w, a0);  \
        a1 = fmaf(w_1_##K##x, hv.x, a1); a1 = fmaf(w_1_##K##y, hv.y, a1);  \
        a1 = fmaf(w_1_##K##z, hv.z, a1); a1 = fmaf(w_1_##K##w, hv.w, a1);  \
        a2 = fmaf(w_2_##K##x, hv.x, a2); a2 = fmaf(w_2_##K##y, hv.y, a2);  \
        a2 = fmaf(w_2_##K##z, hv.z, a2); a2 = fmaf(w_2_##K##w, hv.w, a2);  \
        a3 = fmaf(w_3_##K##x, hv.x, a3); a3 = fmaf(w_3_##K##y, hv.y, a3);  \
        a3 = fmaf(w_3_##K##z, hv.z, a3); a3 = fmaf(w_3_##K##w, hv.w, a3); }
        FMA8(0) FMA8(1) FMA8(2) FMA8(3) FMA8(4) FMA8(5) FMA8(6) FMA8(7)
#undef FMA8
        float4 pv;
        pv.x = a0; pv.y = a1; pv.z = a2; pv.w = a3;
        *(float4*)&part[q][c * 4] = pv;
        __syncthreads();   // barrier #2: part complete

        if (t < 128) {
            // z in ascending-k order (v8-identical arithmetic).
            float z = xp;
#pragma unroll
            for (int qq = 0; qq < 16; ++qq) z += part[qq][t];
            float hn = tanhf(z);

            // Own chunk: register -> LDS direct (self round trip removed).
            h_lds[slice * 128 + t] = hn;
            // Output store (fire & forget).
            outb[(size_t)s * H_DIM + slice * 128 + t] = hn;

            // Publish IMMEDIATELY: pair with neighbor via shfl, 8B exch to
            // the 3 remote consumers only.
            float hn1 = __shfl_down(hn, 1);
            if ((t & 1) == 0) {
                const unsigned long long pv2 =
                    ((unsigned long long)__float_as_uint(hn1) << 32)
                    | (unsigned long long)__float_as_uint(hn);
                const int ph = s & 1;
                const size_t pidx = (size_t)slice * 64 + (t >> 1);
#pragma unroll
                for (int cons = 0; cons < 4; ++cons) {
                    if (cons != slice)
                        atomicExch(mb + ((size_t)(ph * 4 + cons) * B_SZ + b) * 256
                                      + pidx, pv2);
                }
            }
        }
        // No trailing barrier: next step's h_lds writes (pollers + own-chunk)
        // are ordered against this step's h_lds reads by barrier #2, and
        // against next step's FMA reads by barrier #1.
    }
}

// ---------------------------------------------------------------------------
extern "C" void kernel_launch(void* const* d_in, const int* in_sizes, int n_in,
                              void* d_out, int out_size, void* d_ws, size_t ws_size,
                              hipStream_t stream) {
    const float* x_in = (const float*)d_in[0];
    const float* h0   = (const float*)d_in[1];
    const float* W_ih = (const float*)d_in[2];
    const float* W_hh = (const float*)d_in[3];
    const float* b_ih = (const float*)d_in[4];
    const float* b_hh = (const float*)d_in[5];
    float* out = (float*)d_out;
    unsigned long long* mb = (unsigned long long*)d_ws;  // 2*4*64*256*8 = 1 MB

    // 1) x_proj (+biases) straight into d_out.
    dim3 gA(H_DIM / BN, (B_SZ * S_LEN) / BM);
    proj_gemm<<<gA, 256, 0, stream>>>(x_in, W_ih, b_ih, b_hh, out);

    // 2) Arm all mailboxes with the sentinel (both phases).
    hipMemsetAsync(d_ws, 0xAA,
                   (size_t)2 * 4 * B_SZ * 256 * sizeof(unsigned long long),
                   stream);

    // 3) Scan: cooperative launch => co-residency by guarantee.
    void* args[] = {(void*)&W_hh, (void*)&h0, (void*)&out, (void*)&mb};
    hipError_t e = hipLaunchCooperativeKernel(
        (const void*)rnn_scan_v9, dim3(4 * B_SZ), dim3(512), args, 0, stream);
    if (e != hipSuccess) {
        rnn_scan_v9<<<dim3(4 * B_SZ), 512, 0, stream>>>(W_hh, h0, out, mb);
    }
}

// Round 14
// 3408.410 us; speedup vs baseline: 1.3791x; 1.2011x over previous
//
#include <hip/hip_runtime.h>
#include <cstddef>

#define S_LEN 2048
#define B_SZ  64
#define I_DIM 256
#define H_DIM 512

// ---------------------------------------------------------------------------
// Kernel A: projection GEMM (unchanged — validated).
// ---------------------------------------------------------------------------
#define BM 64
#define BN 64
#define BK 32

__global__ __launch_bounds__(256) void proj_gemm(
        const float* __restrict__ X, const float* __restrict__ W,
        const float* __restrict__ b_ih, const float* __restrict__ b_hh,
        float* __restrict__ out) {
    __shared__ float As[BK][BM + 4];
    __shared__ float Bs[BK][BN + 4];

    const int t    = threadIdx.x;
    const int row0 = blockIdx.y * BM;
    const int col0 = blockIdx.x * BN;
    const int ty   = t >> 4;
    const int tx   = t & 15;

    float acc[4][4];
#pragma unroll
    for (int i = 0; i < 4; ++i)
#pragma unroll
        for (int j = 0; j < 4; ++j) acc[i][j] = 0.f;

    for (int kb = 0; kb < I_DIM; kb += BK) {
#pragma unroll
        for (int r = 0; r < 2; ++r) {
            const int idx = t + r * 256;
            const int m   = idx >> 3;
            const int k4  = idx & 7;
            float4 va = *(const float4*)(X + (size_t)(row0 + m) * I_DIM + kb + k4 * 4);
            As[k4 * 4 + 0][m] = va.x;
            As[k4 * 4 + 1][m] = va.y;
            As[k4 * 4 + 2][m] = va.z;
            As[k4 * 4 + 3][m] = va.w;
            float4 vb = *(const float4*)(W + (size_t)(col0 + m) * I_DIM + kb + k4 * 4);
            Bs[k4 * 4 + 0][m] = vb.x;
            Bs[k4 * 4 + 1][m] = vb.y;
            Bs[k4 * 4 + 2][m] = vb.z;
            Bs[k4 * 4 + 3][m] = vb.w;
        }
        __syncthreads();
#pragma unroll
        for (int kk = 0; kk < BK; ++kk) {
            float4 a = *(const float4*)&As[kk][ty * 4];
            float4 b = *(const float4*)&Bs[kk][tx * 4];
            const float av[4] = {a.x, a.y, a.z, a.w};
            const float bv[4] = {b.x, b.y, b.z, b.w};
#pragma unroll
            for (int i = 0; i < 4; ++i)
#pragma unroll
                for (int j = 0; j < 4; ++j)
                    acc[i][j] = fmaf(av[i], bv[j], acc[i][j]);
        }
        __syncthreads();
    }

    float bias[4];
#pragma unroll
    for (int j = 0; j < 4; ++j) {
        const int n = col0 + tx * 4 + j;
        bias[j] = b_ih[n] + b_hh[n];
    }
#pragma unroll
    for (int i = 0; i < 4; ++i) {
        const int m = row0 + ty * 4 + i;
        float4 o;
        o.x = acc[i][0] + bias[0];
        o.y = acc[i][1] + bias[1];
        o.z = acc[i][2] + bias[2];
        o.w = acc[i][3] + bias[3];
        *(float4*)(out + (size_t)m * H_DIM + col0 + tx * 4) = o;
    }
}

// ---------------------------------------------------------------------------
// Kernel B v10: per-WAVE self-synchronized exchange (barrier #1 deleted).
//
// v9 post-mortem: scan 3.94->3.57ms; step 1.74us of which compute ~0.3us =>
// ~1.4us is fabric (publish-complete + poll-detect + queueing). Double-pump
// poll was useless (same-address exchs serialize; WRITE_SIZE rose 1GB).
// Streaming-W alternatives are dead: per-CU L2 port ~138GB/s (v6 measured)
// => 768KB/step = 5us. The lever is the sync chain.
//
// v10: each wave w needs exactly h[64w..64w+64) (its 2 k-chunks q=2w,2w+1).
//  - Mailbox per (phase, wg, batch, WAVE): 32 pairs (8B each). Lanes 0-31 of
//    a remote wave poll one pair each (single-pump exch-RMW, re-arms slot),
//    ds_write it into the wave's PRIVATE h_lds region [64w..64w+64), then
//    the wave's own ds_reads consume it: wave-lockstep + per-WAVE lgkmcnt
//    ordering => NO __syncthreads between poll and FMA.
//  - Producer (t<128, even): pair (hn_t, hn_{t+1}) -> consumer wave
//    w* = 2*slice + (t>=64), pair pw = (t>>1)&31, one exch per remote wg
//    (fan-out 3). Symmetry: consumer wave w lane l expects h[64w+2l..+1]
//    = producer's (m=128*slice+t): w=m>>6, l=(t>>1)&31. Verified.
//  - Own-slice waves (w>>1==slice) read producer's h_lds write from the
//    previous iteration (ordered by B1 + tail B2).
//  - Barriers/step: 2 (part-reduce B1 + h_lds-visibility B2), but neither
//    sits between publish and remote detect: publish happens before B2 and
//    remote polls start right after B2, so fabric overlaps the barriers.
// Protocol invariants (v6-proven): one writer + one reader per address,
// 2-phase, RMW both sides; poll->publish order enforced by B1's vmcnt drain.
// FMA/reduce/tanh arithmetic identical to v8/v9 (passing).
//
// Round-11 audit (container-failure triage): no deadlock possible (4M-iter
// bail + alive=false latch); mailbox max index = 1MB exactly; shfl pairs
// never cross wave boundary; coop-launch-under-capture proven by v6/v8.
// ---------------------------------------------------------------------------
#define SENT2 0xAAAAAAAAAAAAAAAAull

__global__ __launch_bounds__(512, 2) void rnn_scan_v10(
        const float* __restrict__ W_hh, const float* __restrict__ h0,
        float* __restrict__ out, unsigned long long* __restrict__ mb) {
    const int bid   = blockIdx.x;
    const int b     = bid & 63;   // batch ({b,b+64,b+128,b+192} same XCD heuristic)
    const int slice = bid >> 6;   // 0..3: output column slice of 128
    const int t     = threadIdx.x;

    // FMA decomposition (v8-identical): 4 cols x 32 k per thread.
    const int c  = t & 31;
    const int q  = t >> 5;        // k-chunk 0..15
    const int colbase = slice * 128 + c * 4;

    const int w    = t >> 6;      // wave 0..7 (covers chunks 2w, 2w+1)
    const int lane = t & 63;
    const bool own_wave = ((w >> 1) == slice);  // wave-uniform

    __shared__ __align__(16) float h_lds[H_DIM];
    __shared__ __align__(16) float part[16][128];

    // --- W load + scalar pins (v8-identical; W register/AGPR-resident) ----
    const float4* w0p = (const float4*)(W_hh + (size_t)(colbase + 0) * H_DIM + q * 32);
    const float4* w1p = (const float4*)(W_hh + (size_t)(colbase + 1) * H_DIM + q * 32);
    const float4* w2p = (const float4*)(W_hh + (size_t)(colbase + 2) * H_DIM + q * 32);
    const float4* w3p = (const float4*)(W_hh + (size_t)(colbase + 3) * H_DIM + q * 32);

#define WLOAD(R,K) \
    float w_##R##_##K##x, w_##R##_##K##y, w_##R##_##K##z, w_##R##_##K##w; \
    { const float4 v_ = w##R##p[K]; \
      w_##R##_##K##x = v_.x; w_##R##_##K##y = v_.y; \
      w_##R##_##K##z = v_.z; w_##R##_##K##w = v_.w; }
#define WROW(R) WLOAD(R,0) WLOAD(R,1) WLOAD(R,2) WLOAD(R,3) \
                WLOAD(R,4) WLOAD(R,5) WLOAD(R,6) WLOAD(R,7)
    WROW(0) WROW(1) WROW(2) WROW(3)
#undef WROW
#undef WLOAD

#define PIN(R,K) asm volatile("" : "+v"(w_##R##_##K##x), "+v"(w_##R##_##K##y), \
                                   "+v"(w_##R##_##K##z), "+v"(w_##R##_##K##w));
#define PINROW(R) PIN(R,0) PIN(R,1) PIN(R,2) PIN(R,3) \
                  PIN(R,4) PIN(R,5) PIN(R,6) PIN(R,7)
    PINROW(0) PINROW(1) PINROW(2) PINROW(3)
#undef PINROW
#undef PIN

    h_lds[t] = h0[(size_t)b * H_DIM + t];
    __syncthreads();

    float* outb = out + (size_t)b * (size_t)S_LEN * H_DIM;
    bool alive = true;

    // Mailbox: mb[ph(2)][wg(4)][b(64)][wave(8)][pair(32)] (ull), 1 MB total.

    for (int s = 0; s < S_LEN; ++s) {
        // xp prefetch (t<128), overlaps the poll.
        float xp = 0.f;
        if (t < 128) xp = outb[(size_t)s * H_DIM + slice * 128 + t];

        if (s > 0 && !own_wave) {
            // Remote wave: lanes 0-31 poll one pair each, deposit into the
            // wave's private h_lds region. Wave-lockstep + per-wave lgkmcnt
            // => no workgroup barrier needed before the FMA reads below.
            if (lane < 32) {
                const int ph = (s - 1) & 1;
                unsigned long long* src =
                    mb + (((size_t)ph * 4 + slice) * B_SZ + b) * 256
                       + (size_t)w * 32 + lane;
                unsigned long long v = SENT2;
                if (alive) {
                    int it = 0;
                    do {
                        v = atomicExch(src, SENT2);   // RMW; re-arms slot
                        if (v != SENT2) break;
                    } while (++it < 4000000);
                    if (v == SENT2) alive = false;    // bail, never hang
                }
                float2 hv;
                hv.x = __uint_as_float((unsigned)(v & 0xffffffffull));
                hv.y = __uint_as_float((unsigned)(v >> 32));
                *(float2*)&h_lds[64 * w + 2 * lane] = hv;
            }
        }
        // Own-slice waves (and s==0): h_lds already holds the values.

        // Partial dots (v8-identical): 8 broadcast ds_read_b128, 128 FMAs.
        const float4* h4 = (const float4*)&h_lds[q * 32];
        float a0 = 0.f, a1 = 0.f, a2 = 0.f, a3 = 0.f;
#define FMA8(K) { const float4 hv = h4[K];                                 \
        a0 = fmaf(w_0_##K##x, hv.x, a0); a0 = fmaf(w_0_##K##y, hv.y, a0);  \
        a0 = fmaf(w_0_##K##z, hv.z, a0); a0 = fmaf(w_0_##K##w, hv.w, a0);  \
        a1 = fmaf(w_1_##K##x, hv.x, a1); a1 = fmaf(w_1_##K##y, hv.y, a1);  \
        a1 = fmaf(w_1_##K##z, hv.z, a1); a1 = fmaf(w_1_##K##w, hv.w, a1);  \
        a2 = fmaf(w_2_##K##x, hv.x, a2); a2 = fmaf(w_2_##K##y, hv.y, a2);  \
        a2 = fmaf(w_2_##K##z, hv.z, a2); a2 = fmaf(w_2_##K##w, hv.w, a2);  \
        a3 = fmaf(w_3_##K##x, hv.x, a3); a3 = fmaf(w_3_##K##y, hv.y, a3);  \
        a3 = fmaf(w_3_##K##z, hv.z, a3); a3 = fmaf(w_3_##K##w, hv.w, a3); }
        FMA8(0) FMA8(1) FMA8(2) FMA8(3) FMA8(4) FMA8(5) FMA8(6) FMA8(7)
#undef FMA8
        float4 pv;
        pv.x = a0; pv.y = a1; pv.z = a2; pv.w = a3;
        *(float4*)&part[q][c * 4] = pv;
        __syncthreads();   // B1: part complete (also drains poll RMWs
                           //     before any publish below -> ordering).

        if (t < 128) {
            float z = xp;
#pragma unroll
            for (int qq = 0; qq < 16; ++qq) z += part[qq][t];
            float hn = tanhf(z);

            // Output store + own-slice h_lds for next step's own waves.
            outb[(size_t)s * H_DIM + slice * 128 + t] = hn;
            h_lds[slice * 128 + t] = hn;

            // Publish immediately: pair via shfl, one exch per remote wg,
            // addressed to the exact (wave, pair) slot that reads it.
            if (s + 1 < S_LEN) {
                float hn1 = __shfl_down(hn, 1);
                if ((t & 1) == 0) {
                    const unsigned long long pv2 =
                        ((unsigned long long)__float_as_uint(hn1) << 32)
                        | (unsigned long long)__float_as_uint(hn);
                    const int ph  = s & 1;
                    const int wst = 2 * slice + (t >= 64 ? 1 : 0); // target wave
                    const int pw  = (t >> 1) & 31;                 // pair slot
#pragma unroll
                    for (int cons = 0; cons < 4; ++cons) {
                        if (cons != slice)
                            atomicExch(mb + (((size_t)ph * 4 + cons) * B_SZ + b) * 256
                                          + (size_t)wst * 32 + pw, pv2);
                    }
                }
            }
        }
        __syncthreads();   // B2: h_lds own-write visible to own-slice waves;
                           // remote publishes already in flight.
    }
}

// ---------------------------------------------------------------------------
extern "C" void kernel_launch(void* const* d_in, const int* in_sizes, int n_in,
                              void* d_out, int out_size, void* d_ws, size_t ws_size,
                              hipStream_t stream) {
    const float* x_in = (const float*)d_in[0];
    const float* h0   = (const float*)d_in[1];
    const float* W_ih = (const float*)d_in[2];
    const float* W_hh = (const float*)d_in[3];
    const float* b_ih = (const float*)d_in[4];
    const float* b_hh = (const float*)d_in[5];
    float* out = (float*)d_out;
    unsigned long long* mb = (unsigned long long*)d_ws;  // 2*4*64*256*8 = 1 MB

    // 1) x_proj (+biases) straight into d_out.
    dim3 gA(H_DIM / BN, (B_SZ * S_LEN) / BM);
    proj_gemm<<<gA, 256, 0, stream>>>(x_in, W_ih, b_ih, b_hh, out);

    // 2) Arm all mailboxes with the sentinel (both phases).
    hipMemsetAsync(d_ws, 0xAA,
                   (size_t)2 * 4 * B_SZ * 256 * sizeof(unsigned long long),
                   stream);

    // 3) Scan: cooperative launch => co-residency by guarantee.
    void* args[] = {(void*)&W_hh, (void*)&h0, (void*)&out, (void*)&mb};
    hipError_t e = hipLaunchCooperativeKernel(
        (const void*)rnn_scan_v10, dim3(4 * B_SZ), dim3(512), args, 0, stream);
    if (e != hipSuccess) {
        rnn_scan_v10<<<dim3(4 * B_SZ), 512, 0, stream>>>(W_hh, h0, out, mb);
    }
}